// Round 1
// baseline (24898.865 us; speedup 1.0000x reference)
//
#include <hip/hip_runtime.h>
#include <hip/hip_bf16.h>
#include <math.h>

// ---------------------------------------------------------------------------
// SimplifiedGateElmanCell: spectral-norm W_h, Wx = x@W_x^T (big GEMM),
// sequential gated-Elman recurrence with persistent cooperative kernel.
// T=2048, B=32, D=1024. Outputs fp32: out [T,B,D] then h [T+1,B,D].
//
// R1 change: k_rec cross-block sync reworked. Old: 128 fetch_adds/step to ONE
// word (serialized RMWs at coherence point ~= 13us/step). New: per-wave
// release flag stores to distinct words (parity double-buffer, value=step#),
// 128-thread parallel acquire spin; flag signal moved BEFORE outp/hist HBM
// stores and silu so the release's vmcnt(0) drain only covers comm traffic.
// ---------------------------------------------------------------------------

typedef __attribute__((ext_vector_type(8))) short short8;      // 8 x bf16 (MFMA frag)
typedef __attribute__((ext_vector_type(4))) float float4v;     // MFMA acc / vec loads
typedef __attribute__((ext_vector_type(4))) unsigned short ushort4v;

#define AGENT __HIP_MEMORY_SCOPE_AGENT

__device__ __forceinline__ unsigned short f2bf(float f) {
  unsigned int u = __builtin_bit_cast(unsigned int, f);
  u += 0x7fffu + ((u >> 16) & 1u);          // round-to-nearest-even
  return (unsigned short)(u >> 16);
}

__device__ __forceinline__ float wave_red(float v) {
#pragma unroll
  for (int off = 32; off; off >>= 1) v += __shfl_down(v, off);
  return v;
}

// cross-block barrier: single-use epoch counters (zeroed by memset each launch)
__device__ __forceinline__ void gbar(int* bar, int n) {
  __syncthreads();
  if (threadIdx.x == 0) {
    __hip_atomic_fetch_add(bar, 1, __ATOMIC_ACQ_REL, AGENT);
    while (__hip_atomic_load(bar, __ATOMIC_ACQUIRE, AGENT) < n)
      __builtin_amdgcn_s_sleep(2);
  }
  __syncthreads();
}

// ---------------------------------------------------------------------------
// Power iteration (exact reference semantics). 128 blocks x 256.
// wsh: [0..15]=bar counters(int) [16..23]=sum-sq accumulators [24]=scale
// vecs: 6 x 1024 floats (vraw1,uraw1,vraw2,uraw2,vraw3,uraw3)
// ---------------------------------------------------------------------------
__global__ __launch_bounds__(256) void k_power(const float* __restrict__ Wh,
                                               const float* __restrict__ u0f,
                                               float* __restrict__ wsh,
                                               float* __restrict__ vecs) {
  int* bars = (int*)wsh;
  float* nrms = wsh + 16;
  const int bid = blockIdx.x, tid = threadIdx.x;
  const int j0 = bid * 8;
  __shared__ float red[4][8];

  if (bid == 0) {  // ||u0||^2
    float p = 0.f;
    for (int k = tid; k < 1024; k += 256) { float xv = u0f[k]; p += xv * xv; }
    p = wave_red(p);
    if ((tid & 63) == 0) red[0][4 + (tid >> 6)] = p;
    __syncthreads();
    if (tid == 0)
      __hip_atomic_fetch_add(&nrms[0], red[0][4] + red[0][5] + red[0][6] + red[0][7],
                             __ATOMIC_RELEASE, AGENT);
  }
  gbar(&bars[0], 128);

#pragma unroll 1
  for (int it = 0; it < 3; ++it) {
    {  // V stage: vraw_j = sum_k W[k][j] * uhat_k ; block owns j0..j0+8
      float ssin = __hip_atomic_load(&nrms[2 * it], __ATOMIC_ACQUIRE, AGENT);
      float nv = sqrtf(ssin);
      float rinv = (it == 0) ? (1.f / nv) : (1.f / (nv + 1e-8f));  // ref: u0 norm has no eps
      const float* invec = (it == 0) ? u0f : (vecs + (size_t)(2 * it - 1) * 1024);
      float acc[8] = {0, 0, 0, 0, 0, 0, 0, 0};
#pragma unroll
      for (int q = 0; q < 4; ++q) {
        int k = tid * 4 + q;
        float xk = (it == 0) ? invec[k]
                             : __hip_atomic_load(&invec[k], __ATOMIC_RELAXED, AGENT);
        xk *= rinv;
        const float4v w0 = *(const float4v*)(Wh + (size_t)k * 1024 + j0);
        const float4v w1 = *(const float4v*)(Wh + (size_t)k * 1024 + j0 + 4);
        acc[0] += xk * w0.x; acc[1] += xk * w0.y; acc[2] += xk * w0.z; acc[3] += xk * w0.w;
        acc[4] += xk * w1.x; acc[5] += xk * w1.y; acc[6] += xk * w1.z; acc[7] += xk * w1.w;
      }
      __syncthreads();
#pragma unroll
      for (int i = 0; i < 8; ++i) {
        float v = wave_red(acc[i]);
        if ((tid & 63) == 0) red[tid >> 6][i] = v;
      }
      __syncthreads();
      if (tid == 0) {
        float ss = 0.f;
        float* outv = vecs + (size_t)(2 * it) * 1024;
#pragma unroll
        for (int i = 0; i < 8; ++i) {
          float s = red[0][i] + red[1][i] + red[2][i] + red[3][i];
          __hip_atomic_store(&outv[j0 + i], s, __ATOMIC_RELAXED, AGENT);
          ss += s * s;
        }
        __hip_atomic_fetch_add(&nrms[2 * it + 1], ss, __ATOMIC_RELEASE, AGENT);
      }
      gbar(&bars[1 + 2 * it], 128);
    }
    {  // N stage: uraw_i = sum_k W[i][k] * vhat_k ; block owns i0..i0+8
      float ssin = __hip_atomic_load(&nrms[2 * it + 1], __ATOMIC_ACQUIRE, AGENT);
      float rinv = 1.f / (sqrtf(ssin) + 1e-8f);
      const float* invec = vecs + (size_t)(2 * it) * 1024;
      int k0 = tid * 4;
      float4v xk;
      xk.x = __hip_atomic_load(&invec[k0 + 0], __ATOMIC_RELAXED, AGENT) * rinv;
      xk.y = __hip_atomic_load(&invec[k0 + 1], __ATOMIC_RELAXED, AGENT) * rinv;
      xk.z = __hip_atomic_load(&invec[k0 + 2], __ATOMIC_RELAXED, AGENT) * rinv;
      xk.w = __hip_atomic_load(&invec[k0 + 3], __ATOMIC_RELAXED, AGENT) * rinv;
      float acc[8];
#pragma unroll
      for (int i = 0; i < 8; ++i) {
        const float4v w = *(const float4v*)(Wh + (size_t)(j0 + i) * 1024 + k0);
        acc[i] = w.x * xk.x + w.y * xk.y + w.z * xk.z + w.w * xk.w;
      }
      __syncthreads();
#pragma unroll
      for (int i = 0; i < 8; ++i) {
        float v = wave_red(acc[i]);
        if ((tid & 63) == 0) red[tid >> 6][i] = v;
      }
      __syncthreads();
      if (tid == 0) {
        float ss = 0.f;
        float* outv = vecs + (size_t)(2 * it + 1) * 1024;
#pragma unroll
        for (int i = 0; i < 8; ++i) {
          float s = red[0][i] + red[1][i] + red[2][i] + red[3][i];
          __hip_atomic_store(&outv[j0 + i], s, __ATOMIC_RELAXED, AGENT);
          ss += s * s;
        }
        __hip_atomic_fetch_add(&nrms[2 * it + 2], ss, __ATOMIC_RELEASE, AGENT);
      }
      gbar(&bars[2 + 2 * it], 128);
    }
  }
  if (bid == 0 && tid == 0) {
    // sigma = u.(Wv) = ||Wv||^2 / (||Wv||+eps)  (algebraically identical to ref)
    float ss6 = __hip_atomic_load(&nrms[6], __ATOMIC_ACQUIRE, AGENT);
    float un = sqrtf(ss6);
    float sigma = ss6 / (un + 1e-8f);
    float scale = 0.99f / (sigma + 1e-8f);
    __hip_atomic_store(&wsh[24], scale, __ATOMIC_RELAXED, AGENT);
  }
}

// ---------------------------------------------------------------------------
// Conversions + init. Grid 1040 x 256.
// ---------------------------------------------------------------------------
__global__ __launch_bounds__(256) void k_prep2(const float* __restrict__ Wh,
                                               const float* __restrict__ Wx,
                                               const float* __restrict__ h0,
                                               const float* __restrict__ wsh,
                                               unsigned short* __restrict__ whn,
                                               unsigned short* __restrict__ wxb,
                                               unsigned short* __restrict__ comm,
                                               float* __restrict__ hist0) {
  const int bid = blockIdx.x, tid = threadIdx.x;
  if (bid < 512) {  // W_h * scale -> bf16 [j][k]
    const float scale = wsh[24];
    size_t off = ((size_t)bid * 256 + tid) * 8;
    float4v a = *(const float4v*)(Wh + off);
    float4v c = *(const float4v*)(Wh + off + 4);
    short8 pk;
    pk[0] = f2bf(a.x * scale); pk[1] = f2bf(a.y * scale);
    pk[2] = f2bf(a.z * scale); pk[3] = f2bf(a.w * scale);
    pk[4] = f2bf(c.x * scale); pk[5] = f2bf(c.y * scale);
    pk[6] = f2bf(c.z * scale); pk[7] = f2bf(c.w * scale);
    *(short8*)(whn + off) = pk;
  } else if (bid < 1024) {  // W_x -> bf16 [j][d]
    size_t off = ((size_t)(bid - 512) * 256 + tid) * 8;
    float4v a = *(const float4v*)(Wx + off);
    float4v c = *(const float4v*)(Wx + off + 4);
    short8 pk;
    pk[0] = f2bf(a.x); pk[1] = f2bf(a.y); pk[2] = f2bf(a.z); pk[3] = f2bf(a.w);
    pk[4] = f2bf(c.x); pk[5] = f2bf(c.y); pk[6] = f2bf(c.z); pk[7] = f2bf(c.w);
    *(short8*)(wxb + off) = pk;
  } else {  // h0 -> history[0] (fp32) + comm slot 0 (bf16)
    size_t off = ((size_t)(bid - 1024) * 256 + tid) * 8;
    float4v a = *(const float4v*)(h0 + off);
    float4v c = *(const float4v*)(h0 + off + 4);
    *(float4v*)(hist0 + off) = a;
    *(float4v*)(hist0 + off + 4) = c;
    short8 pk;
    pk[0] = f2bf(a.x); pk[1] = f2bf(a.y); pk[2] = f2bf(a.z); pk[3] = f2bf(a.w);
    pk[4] = f2bf(c.x); pk[5] = f2bf(c.y); pk[6] = f2bf(c.z); pk[7] = f2bf(c.w);
    *(short8*)(comm + off) = pk;
  }
}

// ---------------------------------------------------------------------------
// Big GEMM: out[m][j] = sum_d x[m][d]*Wx[j][d], m=0..65535. bf16 MFMA.
// 128x128 tile, BK=64, 256 threads (4 waves as 2x2 of 64x64).
// Writes fp32 Wx_all into d_out's out-region (overwritten later by k_rec).
// ---------------------------------------------------------------------------
__global__ __launch_bounds__(256) void k_gemm(const float* __restrict__ x,
                                              const unsigned short* __restrict__ wxb,
                                              float* __restrict__ out) {
  __shared__ unsigned short As[128][72];  // +8 pad
  __shared__ unsigned short Bs[128][72];
  const int tid = threadIdx.x;
  const int m0 = blockIdx.y * 128, n0 = blockIdx.x * 128;
  const int lane = tid & 63, wv = tid >> 6;
  const int l15 = lane & 15, lq = lane >> 4;
  const int mw = (wv & 1) * 64, nw = (wv >> 1) * 64;
  const int ac = tid & 15, ar = tid >> 4;  // A staging: 16 col-groups x 16 rows
  const int bc = tid & 7, br = tid >> 3;   // B staging: 8 col-groups x 32 rows
  float4v acc[4][4] = {};

  for (int k0 = 0; k0 < 1024; k0 += 64) {
#pragma unroll
    for (int r = 0; r < 8; ++r) {
      int row = ar + r * 16;
      const float4v xv = *(const float4v*)(x + (size_t)(m0 + row) * 1024 + k0 + ac * 4);
      ushort4v pk;
      pk.x = f2bf(xv.x); pk.y = f2bf(xv.y); pk.z = f2bf(xv.z); pk.w = f2bf(xv.w);
      *(ushort4v*)(&As[row][ac * 4]) = pk;
    }
#pragma unroll
    for (int r = 0; r < 4; ++r) {
      int row = br + r * 32;
      *(ushort4v*)(&Bs[row][bc * 8]) =
          *(const ushort4v*)(wxb + (size_t)(n0 + row) * 1024 + k0 + bc * 8);
      *(ushort4v*)(&Bs[row][bc * 8 + 4]) =
          *(const ushort4v*)(wxb + (size_t)(n0 + row) * 1024 + k0 + bc * 8 + 4);
    }
    __syncthreads();
#pragma unroll
    for (int kk = 0; kk < 64; kk += 32) {
      short8 af[4], bf[4];
#pragma unroll
      for (int i = 0; i < 4; ++i)
        af[i] = *(const short8*)(&As[mw + i * 16 + l15][kk + lq * 8]);
#pragma unroll
      for (int j = 0; j < 4; ++j)
        bf[j] = *(const short8*)(&Bs[nw + j * 16 + l15][kk + lq * 8]);
#pragma unroll
      for (int i = 0; i < 4; ++i)
#pragma unroll
        for (int j = 0; j < 4; ++j)
          acc[i][j] = __builtin_amdgcn_mfma_f32_16x16x32_bf16(af[i], bf[j], acc[i][j], 0, 0, 0);
    }
    __syncthreads();
  }
#pragma unroll
  for (int i = 0; i < 4; ++i)
#pragma unroll
    for (int j = 0; j < 4; ++j)
#pragma unroll
      for (int r = 0; r < 4; ++r) {
        int row = m0 + mw + i * 16 + lq * 4 + r;
        int col = n0 + nw + j * 16 + l15;
        out[(size_t)row * 1024 + col] = acc[i][j][r];
      }
}

// ---------------------------------------------------------------------------
// Persistent recurrence. 32 blocks x 256 (4 waves; wave = 16 batches x 16 cols).
// W_hn B-frags in registers; h via IC (agent-scope atomics), double-slot comm.
// Sync: per-wave parity flags (value = step#), release store + parallel
// acquire spin. No RMW on the hot path.
// ---------------------------------------------------------------------------
__global__ __launch_bounds__(256, 1) void k_rec(const unsigned short* __restrict__ whn,
                                                const float* __restrict__ bb,
                                                const float* __restrict__ bgt,
                                                float* __restrict__ dout,
                                                unsigned short* __restrict__ comm,
                                                int* __restrict__ flags) {
  const int tid = threadIdx.x, lane = tid & 63, wv = tid >> 6;
  const int l15 = lane & 15, lq = lane >> 4;
  const int m0 = (wv & 1) * 16;                       // batch tile
  const int jj = blockIdx.x * 32 + (wv >> 1) * 16 + l15;  // output column
  const int brow = m0 + lq * 4;                       // first acc batch row
  const int wid = blockIdx.x * 4 + wv;                // global wave id 0..127
  float* outp = dout;
  float* hist = dout + (size_t)2048 * 32768;

  short8 bw[32];  // B-frags: whn[jj][k], k-chunk t -> registers, resident all steps
#pragma unroll
  for (int t = 0; t < 32; ++t)
    bw[t] = *(const short8*)(whn + (size_t)jj * 1024 + t * 32 + lq * 8);
  const float bjv = bb[jj], bgv = bgt[jj];

  float wxv[4], wxn[4];
#pragma unroll
  for (int i = 0; i < 4; ++i) wxv[i] = outp[(size_t)(brow + i) * 1024 + jj];

  const unsigned long long* commq = (const unsigned long long*)comm;

  for (int s = 0; s < 2048; ++s) {
    if (s + 1 < 2048) {  // prefetch next Wx slice (HBM latency hidden by step work)
#pragma unroll
      for (int i = 0; i < 4; ++i)
        wxn[i] = outp[((size_t)(s + 1) * 32 + brow + i) * 1024 + jj];
    }
    if (s > 0) {
      // wait: all 128 producer waves have signaled step s (parity slot s&1,
      // monotone value >= s; slot reuse safe with 2-step separation)
      if (tid < 128) {
        while (__hip_atomic_load(&flags[(s & 1) * 128 + tid], __ATOMIC_ACQUIRE, AGENT) < s)
          __builtin_amdgcn_s_sleep(1);
      }
      __syncthreads();
    }
    // A-frags straight from IC comm buffer (layout [b][k] bf16, fragment-addressed)
    const unsigned long long* cb =
        commq + (size_t)(s & 1) * 8192 + (size_t)(m0 + l15) * 256 + lq * 2;
    float4v a0 = {0.f, 0.f, 0.f, 0.f}, a1 = a0, a2 = a0, a3 = a0;
#pragma unroll
    for (int t = 0; t < 32; t += 4) {
      union { unsigned long long q[2]; short8 s8; } f0, f1, f2, f3;
      f0.q[0] = __hip_atomic_load(cb + (t + 0) * 8,     __ATOMIC_RELAXED, AGENT);
      f0.q[1] = __hip_atomic_load(cb + (t + 0) * 8 + 1, __ATOMIC_RELAXED, AGENT);
      f1.q[0] = __hip_atomic_load(cb + (t + 1) * 8,     __ATOMIC_RELAXED, AGENT);
      f1.q[1] = __hip_atomic_load(cb + (t + 1) * 8 + 1, __ATOMIC_RELAXED, AGENT);
      f2.q[0] = __hip_atomic_load(cb + (t + 2) * 8,     __ATOMIC_RELAXED, AGENT);
      f2.q[1] = __hip_atomic_load(cb + (t + 2) * 8 + 1, __ATOMIC_RELAXED, AGENT);
      f3.q[0] = __hip_atomic_load(cb + (t + 3) * 8,     __ATOMIC_RELAXED, AGENT);
      f3.q[1] = __hip_atomic_load(cb + (t + 3) * 8 + 1, __ATOMIC_RELAXED, AGENT);
      a0 = __builtin_amdgcn_mfma_f32_16x16x32_bf16(f0.s8, bw[t + 0], a0, 0, 0, 0);
      a1 = __builtin_amdgcn_mfma_f32_16x16x32_bf16(f1.s8, bw[t + 1], a1, 0, 0, 0);
      a2 = __builtin_amdgcn_mfma_f32_16x16x32_bf16(f2.s8, bw[t + 2], a2, 0, 0, 0);
      a3 = __builtin_amdgcn_mfma_f32_16x16x32_bf16(f3.s8, bw[t + 3], a3, 0, 0, 0);
    }
    float4v accv = (a0 + a1) + (a2 + a3);

    // --- critical path first: h (tanh), comm store, flag release ---
    float hv[4];
#pragma unroll
    for (int i = 0; i < 4; ++i) {
      float raw = wxv[i] + accv[i] + bjv;
      float e = __expf(-2.f * fabsf(raw));
      hv[i] = copysignf((1.f - e) / (1.f + e), raw);   // tanh, overflow-safe
    }
    if (s < 2047) {
#pragma unroll
      for (int i = 0; i < 4; ++i)
        __hip_atomic_store(comm + (size_t)((s + 1) & 1) * 32768 + (size_t)(brow + i) * 1024 + jj,
                           f2bf(hv[i]), __ATOMIC_RELAXED, AGENT);
      if (lane == 0)  // per-wave release store: vmcnt drain covers this wave's comm stores
        __hip_atomic_store(&flags[((s + 1) & 1) * 128 + wid], s + 1, __ATOMIC_RELEASE, AGENT);
    }
    // --- off the critical path: silu gate + HBM output stores ---
#pragma unroll
    for (int i = 0; i < 4; ++i) {
      float g = wxv[i] + hv[i] + bgv;
      float o = hv[i] * g / (1.f + __expf(-g));        // h * silu(g)
      size_t rowoff = ((size_t)s * 32 + brow + i) * 1024 + jj;
      outp[rowoff] = o;                                // overwrites consumed Wx[s]
      hist[rowoff + 32768] = hv[i];                    // h[s+1]
    }
#pragma unroll
    for (int i = 0; i < 4; ++i) wxv[i] = wxn[i];
  }
}

// ---------------------------------------------------------------------------
extern "C" void kernel_launch(void* const* d_in, const int* in_sizes, int n_in,
                              void* d_out, int out_size, void* d_ws, size_t ws_size,
                              hipStream_t stream) {
  const float* x   = (const float*)d_in[0];
  // d_in[1] = z : unused by reference (gate_mode 0)
  const float* h0  = (const float*)d_in[2];
  const float* Wx  = (const float*)d_in[3];
  const float* Wh  = (const float*)d_in[4];
  const float* bb  = (const float*)d_in[5];
  const float* bg  = (const float*)d_in[6];
  const float* u0f = (const float*)d_in[7];
  float* out = (float*)d_out;

  char* ws = (char*)d_ws;
  float* wsh           = (float*)ws;                      // bars/nrms/scale (1 KB)
  int* flags           = (int*)(ws + 1024);               // 1 KB: 2 parity slots x 128 waves
  float* vecs          = (float*)(ws + 2048);             // 24 KB power-iter vectors
  unsigned short* whn  = (unsigned short*)(ws + 32768);               // 2 MB
  unsigned short* wxb  = (unsigned short*)(ws + 32768 + 2097152);     // 2 MB
  unsigned short* comm = (unsigned short*)(ws + 32768 + 2 * 2097152); // 128 KB

  hipMemsetAsync(ws, 0, 2048, stream);  // zero barrier counters + norms + flags

  hipLaunchKernelGGL(k_power, dim3(128), dim3(256), 0, stream, Wh, u0f, wsh, vecs);
  hipLaunchKernelGGL(k_prep2, dim3(1040), dim3(256), 0, stream,
                     Wh, Wx, h0, wsh, whn, wxb, comm, out + (size_t)2048 * 32768);
  hipLaunchKernelGGL(k_gemm, dim3(8, 512), dim3(256), 0, stream, x, wxb, out);
  hipLaunchKernelGGL(k_rec, dim3(32), dim3(256), 0, stream, whn, bb, bg, out, comm, flags);
}

// Round 2
// 19642.787 us; speedup vs baseline: 1.2676x; 1.2676x over previous
//
#include <hip/hip_runtime.h>
#include <hip/hip_bf16.h>
#include <math.h>

// ---------------------------------------------------------------------------
// SimplifiedGateElmanCell: spectral-norm W_h, Wx = x@W_x^T (big GEMM),
// sequential gated-Elman recurrence with persistent cooperative kernel.
// T=2048, B=32, D=1024. Outputs fp32: out [T,B,D] then h [T+1,B,D].
//
// R2 change: k_rec restructured 32x256 -> 8x512 (64 waves; wave owns 16 cols
// x all 32 rows, W-slice in 128 regs). h broadcast: per-block cooperative
// bulk load of the 64KB comm slot into XOR-swizzled LDS (ds_read_b128 frags)
// instead of 64 per-wave IC loads interleaved with MFMAs. Comm stores widened
// to dword (shfl_xor pair-packing; no sub-dword atomics). 64 per-wave flags,
// one per 128B cacheline (1 writer + 8 pollers each), relaxed spin + single
// acquire on exit. silu + fp32 out/hist stores after the flag release.
// ---------------------------------------------------------------------------

typedef __attribute__((ext_vector_type(8))) short short8;      // 8 x bf16 (MFMA frag)
typedef __attribute__((ext_vector_type(4))) float float4v;     // MFMA acc / vec loads
typedef __attribute__((ext_vector_type(4))) unsigned short ushort4v;

#define AGENT __HIP_MEMORY_SCOPE_AGENT

__device__ __forceinline__ unsigned short f2bf(float f) {
  unsigned int u = __builtin_bit_cast(unsigned int, f);
  u += 0x7fffu + ((u >> 16) & 1u);          // round-to-nearest-even
  return (unsigned short)(u >> 16);
}

__device__ __forceinline__ float wave_red(float v) {
#pragma unroll
  for (int off = 32; off; off >>= 1) v += __shfl_down(v, off);
  return v;
}

// cross-block barrier: single-use epoch counters (zeroed by memset each launch)
__device__ __forceinline__ void gbar(int* bar, int n) {
  __syncthreads();
  if (threadIdx.x == 0) {
    __hip_atomic_fetch_add(bar, 1, __ATOMIC_ACQ_REL, AGENT);
    while (__hip_atomic_load(bar, __ATOMIC_ACQUIRE, AGENT) < n)
      __builtin_amdgcn_s_sleep(2);
  }
  __syncthreads();
}

// ---------------------------------------------------------------------------
// Power iteration (exact reference semantics). 128 blocks x 256.
// wsh: [0..15]=bar counters(int) [16..23]=sum-sq accumulators [24]=scale
// vecs: 6 x 1024 floats (vraw1,uraw1,vraw2,uraw2,vraw3,uraw3)
// ---------------------------------------------------------------------------
__global__ __launch_bounds__(256) void k_power(const float* __restrict__ Wh,
                                               const float* __restrict__ u0f,
                                               float* __restrict__ wsh,
                                               float* __restrict__ vecs) {
  int* bars = (int*)wsh;
  float* nrms = wsh + 16;
  const int bid = blockIdx.x, tid = threadIdx.x;
  const int j0 = bid * 8;
  __shared__ float red[4][8];

  if (bid == 0) {  // ||u0||^2
    float p = 0.f;
    for (int k = tid; k < 1024; k += 256) { float xv = u0f[k]; p += xv * xv; }
    p = wave_red(p);
    if ((tid & 63) == 0) red[0][4 + (tid >> 6)] = p;
    __syncthreads();
    if (tid == 0)
      __hip_atomic_fetch_add(&nrms[0], red[0][4] + red[0][5] + red[0][6] + red[0][7],
                             __ATOMIC_RELEASE, AGENT);
  }
  gbar(&bars[0], 128);

#pragma unroll 1
  for (int it = 0; it < 3; ++it) {
    {  // V stage: vraw_j = sum_k W[k][j] * uhat_k ; block owns j0..j0+8
      float ssin = __hip_atomic_load(&nrms[2 * it], __ATOMIC_ACQUIRE, AGENT);
      float nv = sqrtf(ssin);
      float rinv = (it == 0) ? (1.f / nv) : (1.f / (nv + 1e-8f));  // ref: u0 norm has no eps
      const float* invec = (it == 0) ? u0f : (vecs + (size_t)(2 * it - 1) * 1024);
      float acc[8] = {0, 0, 0, 0, 0, 0, 0, 0};
#pragma unroll
      for (int q = 0; q < 4; ++q) {
        int k = tid * 4 + q;
        float xk = (it == 0) ? invec[k]
                             : __hip_atomic_load(&invec[k], __ATOMIC_RELAXED, AGENT);
        xk *= rinv;
        const float4v w0 = *(const float4v*)(Wh + (size_t)k * 1024 + j0);
        const float4v w1 = *(const float4v*)(Wh + (size_t)k * 1024 + j0 + 4);
        acc[0] += xk * w0.x; acc[1] += xk * w0.y; acc[2] += xk * w0.z; acc[3] += xk * w0.w;
        acc[4] += xk * w1.x; acc[5] += xk * w1.y; acc[6] += xk * w1.z; acc[7] += xk * w1.w;
      }
      __syncthreads();
#pragma unroll
      for (int i = 0; i < 8; ++i) {
        float v = wave_red(acc[i]);
        if ((tid & 63) == 0) red[tid >> 6][i] = v;
      }
      __syncthreads();
      if (tid == 0) {
        float ss = 0.f;
        float* outv = vecs + (size_t)(2 * it) * 1024;
#pragma unroll
        for (int i = 0; i < 8; ++i) {
          float s = red[0][i] + red[1][i] + red[2][i] + red[3][i];
          __hip_atomic_store(&outv[j0 + i], s, __ATOMIC_RELAXED, AGENT);
          ss += s * s;
        }
        __hip_atomic_fetch_add(&nrms[2 * it + 1], ss, __ATOMIC_RELEASE, AGENT);
      }
      gbar(&bars[1 + 2 * it], 128);
    }
    {  // N stage: uraw_i = sum_k W[i][k] * vhat_k ; block owns i0..i0+8
      float ssin = __hip_atomic_load(&nrms[2 * it + 1], __ATOMIC_ACQUIRE, AGENT);
      float rinv = 1.f / (sqrtf(ssin) + 1e-8f);
      const float* invec = vecs + (size_t)(2 * it) * 1024;
      int k0 = tid * 4;
      float4v xk;
      xk.x = __hip_atomic_load(&invec[k0 + 0], __ATOMIC_RELAXED, AGENT) * rinv;
      xk.y = __hip_atomic_load(&invec[k0 + 1], __ATOMIC_RELAXED, AGENT) * rinv;
      xk.z = __hip_atomic_load(&invec[k0 + 2], __ATOMIC_RELAXED, AGENT) * rinv;
      xk.w = __hip_atomic_load(&invec[k0 + 3], __ATOMIC_RELAXED, AGENT) * rinv;
      float acc[8];
#pragma unroll
      for (int i = 0; i < 8; ++i) {
        const float4v w = *(const float4v*)(Wh + (size_t)(j0 + i) * 1024 + k0);
        acc[i] = w.x * xk.x + w.y * xk.y + w.z * xk.z + w.w * xk.w;
      }
      __syncthreads();
#pragma unroll
      for (int i = 0; i < 8; ++i) {
        float v = wave_red(acc[i]);
        if ((tid & 63) == 0) red[tid >> 6][i] = v;
      }
      __syncthreads();
      if (tid == 0) {
        float ss = 0.f;
        float* outv = vecs + (size_t)(2 * it + 1) * 1024;
#pragma unroll
        for (int i = 0; i < 8; ++i) {
          float s = red[0][i] + red[1][i] + red[2][i] + red[3][i];
          __hip_atomic_store(&outv[j0 + i], s, __ATOMIC_RELAXED, AGENT);
          ss += s * s;
        }
        __hip_atomic_fetch_add(&nrms[2 * it + 2], ss, __ATOMIC_RELEASE, AGENT);
      }
      gbar(&bars[2 + 2 * it], 128);
    }
  }
  if (bid == 0 && tid == 0) {
    // sigma = u.(Wv) = ||Wv||^2 / (||Wv||+eps)  (algebraically identical to ref)
    float ss6 = __hip_atomic_load(&nrms[6], __ATOMIC_ACQUIRE, AGENT);
    float un = sqrtf(ss6);
    float sigma = ss6 / (un + 1e-8f);
    float scale = 0.99f / (sigma + 1e-8f);
    __hip_atomic_store(&wsh[24], scale, __ATOMIC_RELAXED, AGENT);
  }
}

// ---------------------------------------------------------------------------
// Conversions + init. Grid 1040 x 256.
// ---------------------------------------------------------------------------
__global__ __launch_bounds__(256) void k_prep2(const float* __restrict__ Wh,
                                               const float* __restrict__ Wx,
                                               const float* __restrict__ h0,
                                               const float* __restrict__ wsh,
                                               unsigned short* __restrict__ whn,
                                               unsigned short* __restrict__ wxb,
                                               unsigned short* __restrict__ comm,
                                               float* __restrict__ hist0) {
  const int bid = blockIdx.x, tid = threadIdx.x;
  if (bid < 512) {  // W_h * scale -> bf16 [j][k]
    const float scale = wsh[24];
    size_t off = ((size_t)bid * 256 + tid) * 8;
    float4v a = *(const float4v*)(Wh + off);
    float4v c = *(const float4v*)(Wh + off + 4);
    short8 pk;
    pk[0] = f2bf(a.x * scale); pk[1] = f2bf(a.y * scale);
    pk[2] = f2bf(a.z * scale); pk[3] = f2bf(a.w * scale);
    pk[4] = f2bf(c.x * scale); pk[5] = f2bf(c.y * scale);
    pk[6] = f2bf(c.z * scale); pk[7] = f2bf(c.w * scale);
    *(short8*)(whn + off) = pk;
  } else if (bid < 1024) {  // W_x -> bf16 [j][d]
    size_t off = ((size_t)(bid - 512) * 256 + tid) * 8;
    float4v a = *(const float4v*)(Wx + off);
    float4v c = *(const float4v*)(Wx + off + 4);
    short8 pk;
    pk[0] = f2bf(a.x); pk[1] = f2bf(a.y); pk[2] = f2bf(a.z); pk[3] = f2bf(a.w);
    pk[4] = f2bf(c.x); pk[5] = f2bf(c.y); pk[6] = f2bf(c.z); pk[7] = f2bf(c.w);
    *(short8*)(wxb + off) = pk;
  } else {  // h0 -> history[0] (fp32) + comm slot 0 (bf16)
    size_t off = ((size_t)(bid - 1024) * 256 + tid) * 8;
    float4v a = *(const float4v*)(h0 + off);
    float4v c = *(const float4v*)(h0 + off + 4);
    *(float4v*)(hist0 + off) = a;
    *(float4v*)(hist0 + off + 4) = c;
    short8 pk;
    pk[0] = f2bf(a.x); pk[1] = f2bf(a.y); pk[2] = f2bf(a.z); pk[3] = f2bf(a.w);
    pk[4] = f2bf(c.x); pk[5] = f2bf(c.y); pk[6] = f2bf(c.z); pk[7] = f2bf(c.w);
    *(short8*)(comm + off) = pk;
  }
}

// ---------------------------------------------------------------------------
// Big GEMM: out[m][j] = sum_d x[m][d]*Wx[j][d], m=0..65535. bf16 MFMA.
// 128x128 tile, BK=64, 256 threads (4 waves as 2x2 of 64x64).
// Writes fp32 Wx_all into d_out's out-region (overwritten later by k_rec).
// ---------------------------------------------------------------------------
__global__ __launch_bounds__(256) void k_gemm(const float* __restrict__ x,
                                              const unsigned short* __restrict__ wxb,
                                              float* __restrict__ out) {
  __shared__ unsigned short As[128][72];  // +8 pad
  __shared__ unsigned short Bs[128][72];
  const int tid = threadIdx.x;
  const int m0 = blockIdx.y * 128, n0 = blockIdx.x * 128;
  const int lane = tid & 63, wv = tid >> 6;
  const int l15 = lane & 15, lq = lane >> 4;
  const int mw = (wv & 1) * 64, nw = (wv >> 1) * 64;
  const int ac = tid & 15, ar = tid >> 4;  // A staging: 16 col-groups x 16 rows
  const int bc = tid & 7, br = tid >> 3;   // B staging: 8 col-groups x 32 rows
  float4v acc[4][4] = {};

  for (int k0 = 0; k0 < 1024; k0 += 64) {
#pragma unroll
    for (int r = 0; r < 8; ++r) {
      int row = ar + r * 16;
      const float4v xv = *(const float4v*)(x + (size_t)(m0 + row) * 1024 + k0 + ac * 4);
      ushort4v pk;
      pk.x = f2bf(xv.x); pk.y = f2bf(xv.y); pk.z = f2bf(xv.z); pk.w = f2bf(xv.w);
      *(ushort4v*)(&As[row][ac * 4]) = pk;
    }
#pragma unroll
    for (int r = 0; r < 4; ++r) {
      int row = br + r * 32;
      *(ushort4v*)(&Bs[row][bc * 8]) =
          *(const ushort4v*)(wxb + (size_t)(n0 + row) * 1024 + k0 + bc * 8);
      *(ushort4v*)(&Bs[row][bc * 8 + 4]) =
          *(const ushort4v*)(wxb + (size_t)(n0 + row) * 1024 + k0 + bc * 8 + 4);
    }
    __syncthreads();
#pragma unroll
    for (int kk = 0; kk < 64; kk += 32) {
      short8 af[4], bf[4];
#pragma unroll
      for (int i = 0; i < 4; ++i)
        af[i] = *(const short8*)(&As[mw + i * 16 + l15][kk + lq * 8]);
#pragma unroll
      for (int j = 0; j < 4; ++j)
        bf[j] = *(const short8*)(&Bs[nw + j * 16 + l15][kk + lq * 8]);
#pragma unroll
      for (int i = 0; i < 4; ++i)
#pragma unroll
        for (int j = 0; j < 4; ++j)
          acc[i][j] = __builtin_amdgcn_mfma_f32_16x16x32_bf16(af[i], bf[j], acc[i][j], 0, 0, 0);
    }
    __syncthreads();
  }
#pragma unroll
  for (int i = 0; i < 4; ++i)
#pragma unroll
    for (int j = 0; j < 4; ++j)
#pragma unroll
      for (int r = 0; r < 4; ++r) {
        int row = m0 + mw + i * 16 + lq * 4 + r;
        int col = n0 + nw + j * 16 + l15;
        out[(size_t)row * 1024 + col] = acc[i][j][r];
      }
}

// ---------------------------------------------------------------------------
// Persistent recurrence. 8 blocks x 512 (8 waves; wave = 16 cols x 32 rows).
// W_hn B-frags resident in registers (128/wave). h broadcast per step:
// producers store packed dword bf16 pairs to the parity comm slot (IC),
// each block bulk-loads the full 64KB slot cooperatively into XOR-swizzled
// LDS, waves read A-frags via ds_read_b128. 64 per-wave flags, 128B apart.
// ---------------------------------------------------------------------------
__global__ __launch_bounds__(512, 1) void k_rec(const unsigned short* __restrict__ whn,
                                                const float* __restrict__ bb,
                                                const float* __restrict__ bgt,
                                                float* __restrict__ dout,
                                                unsigned short* __restrict__ comm,
                                                int* __restrict__ flags) {
  const int tid = threadIdx.x, lane = tid & 63, wv = tid >> 6;
  const int l15 = lane & 15, lq = lane >> 4;
  const int gw = blockIdx.x * 8 + wv;        // global wave 0..63
  const int jj = gw * 16 + l15;              // output column
  float* outp = dout;
  float* hist = dout + (size_t)2048 * 32768;

  __shared__ __attribute__((aligned(16))) char hlds[65536];  // h [32][1024] bf16, swizzled

  short8 bw[32];  // B-frags: whn[jj][k], k-chunk t -> registers, resident all steps
#pragma unroll
  for (int t = 0; t < 32; ++t)
    bw[t] = *(const short8*)(whn + (size_t)jj * 1024 + t * 32 + lq * 8);
  const float bjv = bb[jj], bgv = bgt[jj];

  // lane's 8 output rows: r<4 -> row lq*4+r (tile0), r>=4 -> 16+lq*4+(r-4) (tile1)
  float wxv[8], wxn[8];
#pragma unroll
  for (int r = 0; r < 8; ++r) {
    int row = (r >> 2) * 16 + lq * 4 + (r & 3);
    wxv[r] = outp[(size_t)row * 1024 + jj];
  }

  const unsigned long long* commq = (const unsigned long long*)comm;
  unsigned int* commw = (unsigned int*)comm;

  for (int s = 0; s < 2048; ++s) {
    if (s + 1 < 2048) {  // prefetch next Wx slice (HBM latency hidden by step work)
#pragma unroll
      for (int r = 0; r < 8; ++r) {
        int row = (r >> 2) * 16 + lq * 4 + (r & 3);
        wxn[r] = outp[((size_t)(s + 1) * 32 + row) * 1024 + jj];
      }
    }
    if (s > 0) {
      // wait: all 64 producer waves have signaled step s (parity slot s&1,
      // monotone value >= s; slot reuse safe with 2-step separation).
      // Relaxed spin (one poller per flag line), single acquire on exit.
      if (tid < 64) {
        const int* fp = flags + (s & 1) * 2048 + tid * 32;
        while (__hip_atomic_load(fp, __ATOMIC_RELAXED, AGENT) < s) {}
        (void)__hip_atomic_load(fp, __ATOMIC_ACQUIRE, AGENT);
      }
    }
    __syncthreads();
    // bulk load comm[s&1] (64KB) -> LDS, XOR-swizzled (byte ^= (row&15)<<4)
    {
      const unsigned long long* src = commq + (size_t)(s & 1) * 8192;
      unsigned long long tv[16];
#pragma unroll
      for (int p = 0; p < 16; ++p)
        tv[p] = __hip_atomic_load(src + p * 512 + tid, __ATOMIC_RELAXED, AGENT);
#pragma unroll
      for (int p = 0; p < 16; ++p) {
        int idx = p * 512 + tid;
        int row = idx >> 8;
        int byte = (row * 2048 + (idx & 255) * 8) ^ ((row & 15) << 4);
        *(unsigned long long*)(hlds + byte) = tv[p];
      }
    }
    __syncthreads();
    // MFMA: 2 row-tiles x 32 k-chunks, 4 accumulation chains
    float4v z = {0.f, 0.f, 0.f, 0.f};
    float4v a00 = z, a01 = z, a10 = z, a11 = z;
    const int swz = (l15 & 15) << 4;   // same for row l15 and 16+l15
#pragma unroll
    for (int t = 0; t < 32; t += 2) {
      int kb0 = t * 64 + lq * 16;
      int kb1 = kb0 + 64;
      short8 f00 = *(const short8*)(hlds + ((l15 * 2048 + kb0) ^ swz));
      short8 f10 = *(const short8*)(hlds + (((16 + l15) * 2048 + kb0) ^ swz));
      short8 f01 = *(const short8*)(hlds + ((l15 * 2048 + kb1) ^ swz));
      short8 f11 = *(const short8*)(hlds + (((16 + l15) * 2048 + kb1) ^ swz));
      a00 = __builtin_amdgcn_mfma_f32_16x16x32_bf16(f00, bw[t], a00, 0, 0, 0);
      a10 = __builtin_amdgcn_mfma_f32_16x16x32_bf16(f10, bw[t], a10, 0, 0, 0);
      a01 = __builtin_amdgcn_mfma_f32_16x16x32_bf16(f01, bw[t + 1], a01, 0, 0, 0);
      a11 = __builtin_amdgcn_mfma_f32_16x16x32_bf16(f11, bw[t + 1], a11, 0, 0, 0);
    }
    float4v acc0 = a00 + a01;   // tile0: rows lq*4+i
    float4v acc1 = a10 + a11;   // tile1: rows 16+lq*4+i

    // --- critical path: h (tanh), packed comm stores, per-wave flag release ---
    float hv[8];
#pragma unroll
    for (int i = 0; i < 4; ++i) {
      float raw0 = wxv[i] + acc0[i] + bjv;
      float e0 = __expf(-2.f * fabsf(raw0));
      hv[i] = copysignf((1.f - e0) / (1.f + e0), raw0);
      float raw1 = wxv[4 + i] + acc1[i] + bjv;
      float e1 = __expf(-2.f * fabsf(raw1));
      hv[4 + i] = copysignf((1.f - e1) / (1.f + e1), raw1);
    }
    if (s < 2047) {
      unsigned int* cw = commw + (size_t)(((s + 1) & 1)) * 16384;
#pragma unroll
      for (int i = 0; i < 4; ++i) {
        // pack (col jj&~1, col jj|1) bf16 pair; both lanes of a pair hold it
        float p0 = __shfl_xor(hv[i], 1);
        unsigned int aa = f2bf(hv[i]), pp = f2bf(p0);
        unsigned int w0 = (l15 & 1) ? ((aa << 16) | pp) : ((pp << 16) | aa);
        float p1 = __shfl_xor(hv[4 + i], 1);
        unsigned int cc = f2bf(hv[4 + i]), qq = f2bf(p1);
        unsigned int w1 = (l15 & 1) ? ((cc << 16) | qq) : ((qq << 16) | cc);
        int r0 = lq * 4 + i, r1 = 16 + lq * 4 + i;
        if (!(l15 & 1))
          __hip_atomic_store(cw + r0 * 512 + (jj >> 1), w0, __ATOMIC_RELAXED, AGENT);
        else
          __hip_atomic_store(cw + r1 * 512 + (jj >> 1), w1, __ATOMIC_RELAXED, AGENT);
      }
      if (lane == 0)  // per-wave release store: drains this wave's comm stores
        __hip_atomic_store(flags + (((s + 1) & 1)) * 2048 + gw * 32, s + 1,
                           __ATOMIC_RELEASE, AGENT);
    }
    // --- off the critical path: silu gate + fp32 HBM output stores ---
#pragma unroll
    for (int r = 0; r < 8; ++r) {
      int row = (r >> 2) * 16 + lq * 4 + (r & 3);
      float g = wxv[r] + hv[r] + bgv;
      float o = hv[r] * g / (1.f + __expf(-g));      // h * silu(g)
      size_t off = ((size_t)s * 32 + row) * 1024 + jj;
      outp[off] = o;                                  // overwrites consumed Wx[s]
      hist[off + 32768] = hv[r];                      // h[s+1]
    }
#pragma unroll
    for (int r = 0; r < 8; ++r) wxv[r] = wxn[r];
  }
}

// ---------------------------------------------------------------------------
extern "C" void kernel_launch(void* const* d_in, const int* in_sizes, int n_in,
                              void* d_out, int out_size, void* d_ws, size_t ws_size,
                              hipStream_t stream) {
  const float* x   = (const float*)d_in[0];
  // d_in[1] = z : unused by reference (gate_mode 0)
  const float* h0  = (const float*)d_in[2];
  const float* Wx  = (const float*)d_in[3];
  const float* Wh  = (const float*)d_in[4];
  const float* bb  = (const float*)d_in[5];
  const float* bg  = (const float*)d_in[6];
  const float* u0f = (const float*)d_in[7];
  float* out = (float*)d_out;

  char* ws = (char*)d_ws;
  float* wsh           = (float*)ws;                      // bars/nrms/scale (1 KB)
  int* flags           = (int*)(ws + 1024);               // 16 KB: 2 parity x 64 waves x 128B
  float* vecs          = (float*)(ws + 17408);            // 24 KB power-iter vectors
  unsigned short* whn  = (unsigned short*)(ws + 49152);               // 2 MB
  unsigned short* wxb  = (unsigned short*)(ws + 49152 + 2097152);     // 2 MB
  unsigned short* comm = (unsigned short*)(ws + 49152 + 2 * 2097152); // 128 KB

  hipMemsetAsync(ws, 0, 17408, stream);  // zero barrier counters + norms + flags

  hipLaunchKernelGGL(k_power, dim3(128), dim3(256), 0, stream, Wh, u0f, wsh, vecs);
  hipLaunchKernelGGL(k_prep2, dim3(1040), dim3(256), 0, stream,
                     Wh, Wx, h0, wsh, whn, wxb, comm, out + (size_t)2048 * 32768);
  hipLaunchKernelGGL(k_gemm, dim3(8, 512), dim3(256), 0, stream, x, wxb, out);
  hipLaunchKernelGGL(k_rec, dim3(8), dim3(512), 0, stream, whn, bb, bg, out, comm, flags);
}